// Round 4
// baseline (310.658 us; speedup 1.0000x reference)
//
#include <hip/hip_runtime.h>

// XSimGCL / LightGCN propagation on MI355X.
// w = D^{-1/2} x  =>  each layer is an unweighted neighbor MEAN; no edge values.
// State = packed bf16 pairs, 128B rows.
// r16 lesson: fp8 e4m3 state FAILED accuracy (7.8e-7 > 3.1e-7): relative quant
//   noise does NOT average down through mean-propagation. State stays bf16.
// r17: layer-3 batch-restricted (2B rows) — worked as modeled (-57us).
// r18: T=512 build, gcur offsets+memset, fused L3+readout (-16us; less than
//   predicted -> build is latency/occupancy bound, not traffic bound).
// r19: csr occupancy attack: DROP outst LDS staging (col_idx region is a dense
//   contiguous <=48KB window -> L2 write-combining already yields full-line
//   evictions; staging redundant). LDS 52->3.4KB, 3->4 blk/CU (24->32 waves),
//   one fewer 12K-entry pass. Item-buckets-first order (bimodal cost, pack the
//   tail). split TP 3584 (38.9KB LDS -> 4 blk/CU). readout 8 pairs / 128 thr.
// spmm L1/L2: at structural fill floor (~183MB/layer = 8 XCD x state + col_idx,
//   ~3.27 TB/s random-128B fill, r13/r14-confirmed). octet-per-row on ADJACENT
//   rows, unroll-4. Build: split-capacity buckets (r10: CAPU 8192/CAPI 12288),
//   wave-shuffle scans; w0 fused into csr (float4 loads).

#define EMBED_DIM 64
#define NUM_LAYERS 3
#define RSHIFT 8            // 256 rows per bucket
#define RMASK 255
#define NBMAX 640           // supports N <= 163840
#define CAPU 8192           // user-bucket capacity (mean 5120)
#define CAPI 12288          // item-bucket capacity (mean 10240)
#define TP 3584             // base pairs per tile -> 2*TP staged entries

__device__ __forceinline__ int bucket_base(int b, int BSPLIT) {
    int lo = (b < BSPLIT) ? b : BSPLIT;
    int hi = (b > BSPLIT) ? (b - BSPLIT) : 0;
    return lo * CAPU + hi * CAPI;
}

// ---------------- bf16 pair helpers ----------------

__device__ __forceinline__ unsigned bf16pair(float a, float b) {
    unsigned ia = __float_as_uint(a);
    unsigned ib = __float_as_uint(b);
    ia = (ia + 0x7fffu + ((ia >> 16) & 1u)) >> 16;          // RNE, low half
    ib = (ib + 0x7fffu + ((ib >> 16) & 1u)) & 0xffff0000u;  // RNE, high half
    return ia | ib;
}
__device__ __forceinline__ float bf_lo(unsigned u) { return __uint_as_float(u << 16); }
__device__ __forceinline__ float bf_hi(unsigned u) { return __uint_as_float(u & 0xffff0000u); }

// ---------------- split: pairs -> 2 entries -> LDS bucket-grouped -> run copies ----------------
// T=512, TP=3584 (38.9KB LDS -> 4 blk/CU = 32 waves).
// gcur[b] holds per-bucket OFFSET (memset-0 before launch).

__global__ __launch_bounds__(512) void split_kernel(const int* __restrict__ uu,
                                                    const int* __restrict__ vv,
                                                    int* __restrict__ gcur,
                                                    int* __restrict__ bin, int E2, int NB,
                                                    int BSPLIT) {
    __shared__ int h[NBMAX], exl[NBMAX], curb[NBMAX], gb[NBMAX];
    __shared__ int wp[8];
    __shared__ int stage[2 * TP];
    int tid = threadIdx.x;
    int lane = tid & 63, wid = tid >> 6;
    for (int i = tid; i < NB; i += 512) h[i] = 0;
    __syncthreads();
    int e0 = blockIdx.x * TP, e1 = min(e0 + TP, E2);
    // hist pass (int4-vectorized; e0 is 16B aligned)
    int j = e0 + tid * 4;
    for (; j + 3 < e1; j += 2048) {
        int4 u4 = *(const int4*)(uu + j);
        int4 v4 = *(const int4*)(vv + j);
        atomicAdd(&h[u4.x >> RSHIFT], 1); atomicAdd(&h[v4.x >> RSHIFT], 1);
        atomicAdd(&h[u4.y >> RSHIFT], 1); atomicAdd(&h[v4.y >> RSHIFT], 1);
        atomicAdd(&h[u4.z >> RSHIFT], 1); atomicAdd(&h[v4.z >> RSHIFT], 1);
        atomicAdd(&h[u4.w >> RSHIFT], 1); atomicAdd(&h[v4.w >> RSHIFT], 1);
    }
    for (; j < e1; ++j) {  // tail (last block only)
        atomicAdd(&h[uu[j] >> RSHIFT], 1);
        atomicAdd(&h[vv[j] >> RSHIFT], 1);
    }
    __syncthreads();
    // exclusive scan of h[0..NB) -> exl: 2 elems/thread + wave-shuffle scan
    {
        int b2 = tid * 2;
        int v0 = (b2     < NB) ? h[b2]     : 0;
        int v1 = (b2 + 1 < NB) ? h[b2 + 1] : 0;
        int tsum = v0 + v1;
        int x = tsum;
        for (int off = 1; off < 64; off <<= 1) {
            int y = __shfl_up(x, off, 64);
            if (lane >= off) x += y;
        }
        if (lane == 63) wp[wid] = x;
        __syncthreads();
        int wadd = 0;
        for (int k = 0; k < wid; ++k) wadd += wp[k];
        int tpre = wadd + x - tsum;
        if (b2     < NB) exl[b2]     = tpre;
        if (b2 + 1 < NB) exl[b2 + 1] = tpre + v0;
        __syncthreads();
    }
    for (int b = tid; b < NB; b += 512) {
        curb[b] = exl[b];
        gb[b]   = h[b] ? (bucket_base(b, BSPLIT) + atomicAdd(&gcur[b], h[b])) : 0;
    }
    __syncthreads();
    // scatter pass (int4-vectorized)
    j = e0 + tid * 4;
    for (; j + 3 < e1; j += 2048) {
        int4 u4 = *(const int4*)(uu + j);
        int4 v4 = *(const int4*)(vv + j);
        int p;
        p = atomicAdd(&curb[u4.x >> RSHIFT], 1); stage[p] = (v4.x << RSHIFT) | (u4.x & RMASK);
        p = atomicAdd(&curb[v4.x >> RSHIFT], 1); stage[p] = (u4.x << RSHIFT) | (v4.x & RMASK);
        p = atomicAdd(&curb[u4.y >> RSHIFT], 1); stage[p] = (v4.y << RSHIFT) | (u4.y & RMASK);
        p = atomicAdd(&curb[v4.y >> RSHIFT], 1); stage[p] = (u4.y << RSHIFT) | (v4.y & RMASK);
        p = atomicAdd(&curb[u4.z >> RSHIFT], 1); stage[p] = (v4.z << RSHIFT) | (u4.z & RMASK);
        p = atomicAdd(&curb[v4.z >> RSHIFT], 1); stage[p] = (u4.z << RSHIFT) | (v4.z & RMASK);
        p = atomicAdd(&curb[u4.w >> RSHIFT], 1); stage[p] = (v4.w << RSHIFT) | (u4.w & RMASK);
        p = atomicAdd(&curb[v4.w >> RSHIFT], 1); stage[p] = (u4.w << RSHIFT) | (v4.w & RMASK);
    }
    for (; j < e1; ++j) {
        int u = uu[j], v = vv[j];
        int p1 = atomicAdd(&curb[u >> RSHIFT], 1);
        stage[p1] = (v << RSHIFT) | (u & RMASK);
        int p2 = atomicAdd(&curb[v >> RSHIFT], 1);
        stage[p2] = (u << RSHIFT) | (v & RMASK);
    }
    __syncthreads();
    // copy runs out contiguously — one OCTET per bucket run (runs avg ~12)
    int noct = tid >> 3, osub = tid & 7;
    for (int b = noct; b < NB; b += 64) {
        int cnt_b = h[b];
        int st = exl[b], g = gb[b];
        for (int k = osub; k < cnt_b; k += 8) bin[g + k] = stage[st + k];
    }
}

// ---------------- csr: per-bucket LDS counting sort + fused w0 (T=512) ----------------
// r19: no outst staging — direct col_idx scatter (dense contiguous window ->
// L2 write-combines to full lines). LDS 3.4KB -> 4 blk/CU (32 waves).
// Item buckets (2x cost) scheduled FIRST to pack the tail.

__global__ __launch_bounds__(512) void csr_kernel(const int* __restrict__ bin,
                                                  const int* __restrict__ gcur,
                                                  int* __restrict__ row_ptr,
                                                  int* __restrict__ deg,
                                                  int* __restrict__ col_idx,
                                                  const float4* __restrict__ ue,
                                                  const float4* __restrict__ ie,
                                                  unsigned* __restrict__ w0x,
                                                  int N, int U, int BSPLIT, int NB) {
    __shared__ int h2[256], cur2[256];
    __shared__ float rs2[256];
    __shared__ int wp[8];
    int nbi = NB - BSPLIT;          // item-bucket count
    int bb  = blockIdx.x;
    int b   = (bb < nbi) ? (BSPLIT + bb) : (bb - nbi);   // items first
    int tid = threadIdx.x;
    int lane = tid & 63, wid = tid >> 6;
    int s = bucket_base(b, BSPLIT);
    int cnt = gcur[b];        // bucket count (offset accumulated by split)
    if (tid < 256) h2[tid] = 0;
    __syncthreads();
    // hist pass (int4; s is 16B aligned)
    int cnt4 = cnt >> 2;
    const int4* bin4 = (const int4*)(bin + s);
    for (int j = tid; j < cnt4; j += 512) {
        int4 v = bin4[j];
        atomicAdd(&h2[v.x & RMASK], 1);
        atomicAdd(&h2[v.y & RMASK], 1);
        atomicAdd(&h2[v.z & RMASK], 1);
        atomicAdd(&h2[v.w & RMASK], 1);
    }
    for (int j = (cnt4 << 2) + tid; j < cnt; j += 512) atomicAdd(&h2[bin[s + j] & RMASK], 1);
    __syncthreads();
    int myh = (tid < 256) ? h2[tid] : 0;
    if (tid < 256) rs2[tid] = (myh > 0) ? rsqrtf((float)myh) : 0.0f;
    // exclusive scan of h2 via wave shuffles (first 4 waves carry data)
    {
        int x = myh;
        for (int off = 1; off < 64; off <<= 1) {
            int y = __shfl_up(x, off, 64);
            if (lane >= off) x += y;
        }
        if (lane == 63) wp[wid] = x;
        __syncthreads();
        if (tid < 256) {
            int wadd = 0;
            for (int k = 0; k < wid; ++k) wadd += wp[k];
            cur2[tid] = wadd + x - myh;   // exclusive
        }
    }
    int gr = (b << RSHIFT) + tid;
    if (tid < 256 && gr < N) {
        row_ptr[gr] = s + cur2[tid];
        deg[gr]     = myh;
    }
    __syncthreads();
    // placement pass: direct scatter into col_idx (contiguous <=48KB window)
    for (int j = tid; j < cnt4; j += 512) {
        int4 v = bin4[j];
        int p;
        p = atomicAdd(&cur2[v.x & RMASK], 1); col_idx[s + p] = v.x >> RSHIFT;
        p = atomicAdd(&cur2[v.y & RMASK], 1); col_idx[s + p] = v.y >> RSHIFT;
        p = atomicAdd(&cur2[v.z & RMASK], 1); col_idx[s + p] = v.z >> RSHIFT;
        p = atomicAdd(&cur2[v.w & RMASK], 1); col_idx[s + p] = v.w >> RSHIFT;
    }
    for (int j = (cnt4 << 2) + tid; j < cnt; j += 512) {
        int v = bin[s + j];
        int p = atomicAdd(&cur2[v & RMASK], 1);
        col_idx[s + p] = v >> RSHIFT;
    }
    // fused w0: pack bf16(D^{-1/2} * emb) for this bucket's 256 rows
    // (needs only rs2, already valid — no barrier required)
    for (int idx = tid; idx < 256 * 16; idx += 512) {
        int rl = idx >> 4, sub = idx & 15;
        int n = (b << RSHIFT) + rl;
        if (n < N) {
            float4 v = (n < U) ? ue[(size_t)n * 16 + sub] : ie[(size_t)(n - U) * 16 + sub];
            float rs = rs2[rl];
            uint2 o;
            o.x = bf16pair(v.x * rs, v.y * rs);
            o.y = bf16pair(v.z * rs, v.w * rs);
            ((uint2*)w0x)[(size_t)n * 16 + sub] = o;
        }
    }
}

// ---------------- SpMM: neighbor mean, octet-per-row (adjacent), unroll-4 ----------------

__global__ __launch_bounds__(256) void spmm_kernel(const int* __restrict__ row_ptr,
                                                   const int* __restrict__ deg,
                                                   const int* __restrict__ col_idx,
                                                   const uint4* __restrict__ x4,
                                                   uint4* __restrict__ y4, int N) {
    int gw   = (blockIdx.x * blockDim.x + threadIdx.x) >> 6;
    int lane = threadIdx.x & 63;
    int oct  = lane >> 3, sub = lane & 7;
    int r = gw * 8 + oct;
    if (r >= N) return;
    int s = row_ptr[r];
    int d = deg[r];
    float2 a0 = {0, 0}, a1 = {0, 0}, a2 = {0, 0}, a3 = {0, 0};
    int k = 0;
    for (; k + 3 < d; k += 4) {
        int c0 = col_idx[s + k];
        int c1 = col_idx[s + k + 1];
        int c2 = col_idx[s + k + 2];
        int c3 = col_idx[s + k + 3];
        uint4 u0 = x4[(size_t)c0 * 8 + sub];
        uint4 u1 = x4[(size_t)c1 * 8 + sub];
        uint4 u2 = x4[(size_t)c2 * 8 + sub];
        uint4 u3 = x4[(size_t)c3 * 8 + sub];
        a0.x += bf_lo(u0.x); a0.y += bf_hi(u0.x);
        a1.x += bf_lo(u0.y); a1.y += bf_hi(u0.y);
        a2.x += bf_lo(u0.z); a2.y += bf_hi(u0.z);
        a3.x += bf_lo(u0.w); a3.y += bf_hi(u0.w);
        a0.x += bf_lo(u1.x); a0.y += bf_hi(u1.x);
        a1.x += bf_lo(u1.y); a1.y += bf_hi(u1.y);
        a2.x += bf_lo(u1.z); a2.y += bf_hi(u1.z);
        a3.x += bf_lo(u1.w); a3.y += bf_hi(u1.w);
        a0.x += bf_lo(u2.x); a0.y += bf_hi(u2.x);
        a1.x += bf_lo(u2.y); a1.y += bf_hi(u2.y);
        a2.x += bf_lo(u2.z); a2.y += bf_hi(u2.z);
        a3.x += bf_lo(u2.w); a3.y += bf_hi(u2.w);
        a0.x += bf_lo(u3.x); a0.y += bf_hi(u3.x);
        a1.x += bf_lo(u3.y); a1.y += bf_hi(u3.y);
        a2.x += bf_lo(u3.z); a2.y += bf_hi(u3.z);
        a3.x += bf_lo(u3.w); a3.y += bf_hi(u3.w);
    }
    for (; k < d; ++k) {
        int c0 = col_idx[s + k];
        uint4 u0 = x4[(size_t)c0 * 8 + sub];
        a0.x += bf_lo(u0.x); a0.y += bf_hi(u0.x);
        a1.x += bf_lo(u0.y); a1.y += bf_hi(u0.y);
        a2.x += bf_lo(u0.z); a2.y += bf_hi(u0.z);
        a3.x += bf_lo(u0.w); a3.y += bf_hi(u0.w);
    }
    float inv = (d > 0) ? (1.0f / (float)d) : 0.0f;
    uint4 o;
    o.x = bf16pair(a0.x * inv, a0.y * inv);
    o.y = bf16pair(a1.x * inv, a1.y * inv);
    o.z = bf16pair(a2.x * inv, a2.y * inv);
    o.w = bf16pair(a3.x * inv, a3.y * inv);
    y4[(size_t)r * 8 + sub] = o;
}

// ---------------- fused layer-3 + readout ----------------
// 8 batch pairs per 128-thread block: octets 0-7 = user rows, 8-15 = item rows.
// Each octet computes its row's L3 (mean over neighbors of L2) in f32,
// adds L1+L2 rows, then the dot is reduced via LDS exchange + octet shuffle.

__global__ __launch_bounds__(128) void batch_readout_kernel(const int* __restrict__ row_ptr,
                                                            const int* __restrict__ deg,
                                                            const int* __restrict__ col_idx,
                                                            const uint4* __restrict__ x4,   // L2
                                                            const uint4* __restrict__ l1,
                                                            const uint4* __restrict__ l2,
                                                            const int* __restrict__ user_ids,
                                                            const int* __restrict__ item_ids,
                                                            float* __restrict__ out,
                                                            int B, int U) {
    __shared__ float sm[8][8][8];    // item-side 3-layer sums
    __shared__ float dsm[8];         // item-side degrees
    int tid = threadIdx.x;
    int oct = tid >> 3, sub = tid & 7;
    int pair = oct & 7, is_item = oct >> 3;
    int b = blockIdx.x * 8 + pair;
    bool active = (b < B);
    float sv[8];
#pragma unroll
    for (int k = 0; k < 8; ++k) sv[k] = 0.0f;
    float dd = 0.0f;
    if (active) {
        int r = is_item ? (item_ids[b] + U) : user_ids[b];
        int s = row_ptr[r];
        int d = deg[r];
        dd = (float)d;
        float2 a0 = {0, 0}, a1 = {0, 0}, a2 = {0, 0}, a3 = {0, 0};
        int k = 0;
        for (; k + 3 < d; k += 4) {
            int c0 = col_idx[s + k];
            int c1 = col_idx[s + k + 1];
            int c2 = col_idx[s + k + 2];
            int c3 = col_idx[s + k + 3];
            uint4 u0 = x4[(size_t)c0 * 8 + sub];
            uint4 u1 = x4[(size_t)c1 * 8 + sub];
            uint4 u2 = x4[(size_t)c2 * 8 + sub];
            uint4 u3 = x4[(size_t)c3 * 8 + sub];
            a0.x += bf_lo(u0.x); a0.y += bf_hi(u0.x);
            a1.x += bf_lo(u0.y); a1.y += bf_hi(u0.y);
            a2.x += bf_lo(u0.z); a2.y += bf_hi(u0.z);
            a3.x += bf_lo(u0.w); a3.y += bf_hi(u0.w);
            a0.x += bf_lo(u1.x); a0.y += bf_hi(u1.x);
            a1.x += bf_lo(u1.y); a1.y += bf_hi(u1.y);
            a2.x += bf_lo(u1.z); a2.y += bf_hi(u1.z);
            a3.x += bf_lo(u1.w); a3.y += bf_hi(u1.w);
            a0.x += bf_lo(u2.x); a0.y += bf_hi(u2.x);
            a1.x += bf_lo(u2.y); a1.y += bf_hi(u2.y);
            a2.x += bf_lo(u2.z); a2.y += bf_hi(u2.z);
            a3.x += bf_lo(u2.w); a3.y += bf_hi(u2.w);
            a0.x += bf_lo(u3.x); a0.y += bf_hi(u3.x);
            a1.x += bf_lo(u3.y); a1.y += bf_hi(u3.y);
            a2.x += bf_lo(u3.z); a2.y += bf_hi(u3.z);
            a3.x += bf_lo(u3.w); a3.y += bf_hi(u3.w);
        }
        for (; k < d; ++k) {
            int c0 = col_idx[s + k];
            uint4 u0 = x4[(size_t)c0 * 8 + sub];
            a0.x += bf_lo(u0.x); a0.y += bf_hi(u0.x);
            a1.x += bf_lo(u0.y); a1.y += bf_hi(u0.y);
            a2.x += bf_lo(u0.z); a2.y += bf_hi(u0.z);
            a3.x += bf_lo(u0.w); a3.y += bf_hi(u0.w);
        }
        float inv = (d > 0) ? (1.0f / (float)d) : 0.0f;
        uint4 u1v = l1[(size_t)r * 8 + sub];
        uint4 u2v = l2[(size_t)r * 8 + sub];
        sv[0] = bf_lo(u1v.x) + bf_lo(u2v.x) + a0.x * inv;
        sv[1] = bf_hi(u1v.x) + bf_hi(u2v.x) + a0.y * inv;
        sv[2] = bf_lo(u1v.y) + bf_lo(u2v.y) + a1.x * inv;
        sv[3] = bf_hi(u1v.y) + bf_hi(u2v.y) + a1.y * inv;
        sv[4] = bf_lo(u1v.z) + bf_lo(u2v.z) + a2.x * inv;
        sv[5] = bf_hi(u1v.z) + bf_hi(u2v.z) + a2.y * inv;
        sv[6] = bf_lo(u1v.w) + bf_lo(u2v.w) + a3.x * inv;
        sv[7] = bf_hi(u1v.w) + bf_hi(u2v.w) + a3.y * inv;
    }
    if (is_item) {
#pragma unroll
        for (int k = 0; k < 8; ++k) sm[pair][sub][k] = sv[k];
        if (sub == 0) dsm[pair] = dd;
    }
    __syncthreads();
    if (!is_item && active) {
        float p = 0.0f;
#pragma unroll
        for (int k = 0; k < 8; ++k) p += sv[k] * sm[pair][sub][k];
#pragma unroll
        for (int off = 4; off > 0; off >>= 1) p += __shfl_down(p, off, 8);
        if (sub == 0) {
            float du = dd;
            float di = dsm[pair];
            out[b] = p * sqrtf(du) * sqrtf(di) * (1.0f / (NUM_LAYERS * NUM_LAYERS));
        }
    }
}

// ---------------- launch ----------------

extern "C" void kernel_launch(void* const* d_in, const int* in_sizes, int n_in,
                              void* d_out, int out_size, void* d_ws, size_t ws_size,
                              hipStream_t stream) {
    const float* user_emb = (const float*)d_in[0];
    const float* item_emb = (const float*)d_in[1];
    // d_in[2] (vals) unused: reconstructed algebraically from degrees
    const int*   rows     = (const int*)d_in[3];
    const int*   cols     = (const int*)d_in[4];
    const int*   user_ids = (const int*)d_in[5];
    const int*   item_ids = (const int*)d_in[6];
    float*       out      = (float*)d_out;

    const int U = in_sizes[0] / EMBED_DIM;
    const int I = in_sizes[1] / EMBED_DIM;
    const int E2 = in_sizes[3] >> 1;    // base pairs: rows=[u;v'], cols=[v';u]
    const int B = in_sizes[5];
    const int N = U + I;
    const int NB = (N + RMASK) >> RSHIFT;   // 256-row buckets
    const int BSPLIT = U >> RSHIFT;         // buckets below: pure users

    // total bin entries = bucket_base(NB)
    const long long TOT = (long long)((NB < BSPLIT ? NB : BSPLIT)) * CAPU +
                          (long long)((NB > BSPLIT) ? (NB - BSPLIT) : 0) * CAPI;

    // workspace layout (~104MB)
    char* w = (char*)d_ws;
    unsigned* x2      = (unsigned*)w; w += (size_t)N * 32 * sizeof(unsigned);   // w0
    unsigned* L1      = (unsigned*)w; w += (size_t)N * 32 * sizeof(unsigned);
    unsigned* L2      = (unsigned*)w; w += (size_t)N * 32 * sizeof(unsigned);
    int*      bin     = (int*)w;      w += (size_t)TOT * sizeof(int);
    int*      col_idx = (int*)w;      w += (size_t)TOT * sizeof(int);
    int*      row_ptr = (int*)w;      w += (size_t)N * sizeof(int);
    int*      deg     = (int*)w;      w += (size_t)N * sizeof(int);
    int*      gcur    = (int*)w;      w += (size_t)NB * sizeof(int);

    const int GP = (E2 + TP - 1) / TP;

    // CSR build: split-capacity buckets, LDS-staged counting sort, fused w0
    hipMemsetAsync(gcur, 0, (size_t)NB * sizeof(int), stream);
    split_kernel<<<GP, 512, 0, stream>>>(rows, cols, gcur, bin, E2, NB, BSPLIT);
    csr_kernel<<<NB, 512, 0, stream>>>(bin, gcur, row_ptr, deg, col_idx,
                                       (const float4*)user_emb, (const float4*)item_emb,
                                       x2, N, U, BSPLIT, NB);

    // propagation: layers 1-2 full (structural fill floor), layer 3 fused into readout
    const int T = 256;
    const int GS = (N * 8 + T - 1) / T;   // one octet (8 threads) per row
    spmm_kernel<<<GS, T, 0, stream>>>(row_ptr, deg, col_idx,
                                      (const uint4*)x2, (uint4*)L1, N);
    spmm_kernel<<<GS, T, 0, stream>>>(row_ptr, deg, col_idx,
                                      (const uint4*)L1, (uint4*)L2, N);

    batch_readout_kernel<<<(B + 7) / 8, 128, 0, stream>>>(row_ptr, deg, col_idx,
                                                          (const uint4*)L2,
                                                          (const uint4*)L1, (const uint4*)L2,
                                                          user_ids, item_ids, out, B, U);
}

// Round 5
// 287.513 us; speedup vs baseline: 1.0805x; 1.0805x over previous
//
#include <hip/hip_runtime.h>

// XSimGCL / LightGCN propagation on MI355X.
// w = D^{-1/2} x  =>  each layer is an unweighted neighbor MEAN; no edge values.
// State = packed bf16 pairs, 128B rows.
// r16 lesson: fp8 e4m3 state FAILED accuracy: relative quant noise does NOT
//   average down through mean-propagation. State stays bf16.
// r17: layer-3 batch-restricted (2B rows) — worked as modeled (-57us).
// r18: T=512 build, gcur offsets+memset, fused L3+readout (-16us).
// r19 lesson: direct col_idx scatter REGRESSED (+22us): random 4B global
//   writes = 64 L2 transactions/wave vs 4 for the staged coalesced copy.
//   The r4 rule (contiguous runs / full 128B lines for EVERY global write)
//   is load-bearing — do not override it.
// r20: csr outst staging RESTORED (LDS 52KB, 3 blk/CU); keep item-first
//   bucket order, split TP 3584 (4 blk/CU), 128-thr readout to isolate.
// spmm L1/L2: at structural fill floor (~183MB/layer = 8 XCD x state + col_idx,
//   ~3.27 TB/s random-128B fill, r13/r14-confirmed). octet-per-row on ADJACENT
//   rows, unroll-4. Build: split-capacity buckets (r10: CAPU 8192/CAPI 12288),
//   wave-shuffle scans; w0 fused into csr (float4 loads).

#define EMBED_DIM 64
#define NUM_LAYERS 3
#define RSHIFT 8            // 256 rows per bucket
#define RMASK 255
#define NBMAX 640           // supports N <= 163840
#define CAPU 8192           // user-bucket capacity (mean 5120)
#define CAPI 12288          // item-bucket capacity (mean 10240)
#define TP 3584             // base pairs per tile -> 2*TP staged entries
#define OUT_CAP 12288       // csr out-staging capacity (>= worst bucket)

__device__ __forceinline__ int bucket_base(int b, int BSPLIT) {
    int lo = (b < BSPLIT) ? b : BSPLIT;
    int hi = (b > BSPLIT) ? (b - BSPLIT) : 0;
    return lo * CAPU + hi * CAPI;
}

// ---------------- bf16 pair helpers ----------------

__device__ __forceinline__ unsigned bf16pair(float a, float b) {
    unsigned ia = __float_as_uint(a);
    unsigned ib = __float_as_uint(b);
    ia = (ia + 0x7fffu + ((ia >> 16) & 1u)) >> 16;          // RNE, low half
    ib = (ib + 0x7fffu + ((ib >> 16) & 1u)) & 0xffff0000u;  // RNE, high half
    return ia | ib;
}
__device__ __forceinline__ float bf_lo(unsigned u) { return __uint_as_float(u << 16); }
__device__ __forceinline__ float bf_hi(unsigned u) { return __uint_as_float(u & 0xffff0000u); }

// ---------------- split: pairs -> 2 entries -> LDS bucket-grouped -> run copies ----------------
// T=512, TP=3584 (38.9KB LDS -> 4 blk/CU = 32 waves).
// gcur[b] holds per-bucket OFFSET (memset-0 before launch).

__global__ __launch_bounds__(512) void split_kernel(const int* __restrict__ uu,
                                                    const int* __restrict__ vv,
                                                    int* __restrict__ gcur,
                                                    int* __restrict__ bin, int E2, int NB,
                                                    int BSPLIT) {
    __shared__ int h[NBMAX], exl[NBMAX], curb[NBMAX], gb[NBMAX];
    __shared__ int wp[8];
    __shared__ int stage[2 * TP];
    int tid = threadIdx.x;
    int lane = tid & 63, wid = tid >> 6;
    for (int i = tid; i < NB; i += 512) h[i] = 0;
    __syncthreads();
    int e0 = blockIdx.x * TP, e1 = min(e0 + TP, E2);
    // hist pass (int4-vectorized; e0 is 16B aligned)
    int j = e0 + tid * 4;
    for (; j + 3 < e1; j += 2048) {
        int4 u4 = *(const int4*)(uu + j);
        int4 v4 = *(const int4*)(vv + j);
        atomicAdd(&h[u4.x >> RSHIFT], 1); atomicAdd(&h[v4.x >> RSHIFT], 1);
        atomicAdd(&h[u4.y >> RSHIFT], 1); atomicAdd(&h[v4.y >> RSHIFT], 1);
        atomicAdd(&h[u4.z >> RSHIFT], 1); atomicAdd(&h[v4.z >> RSHIFT], 1);
        atomicAdd(&h[u4.w >> RSHIFT], 1); atomicAdd(&h[v4.w >> RSHIFT], 1);
    }
    for (; j < e1; ++j) {  // tail (last block only)
        atomicAdd(&h[uu[j] >> RSHIFT], 1);
        atomicAdd(&h[vv[j] >> RSHIFT], 1);
    }
    __syncthreads();
    // exclusive scan of h[0..NB) -> exl: 2 elems/thread + wave-shuffle scan
    {
        int b2 = tid * 2;
        int v0 = (b2     < NB) ? h[b2]     : 0;
        int v1 = (b2 + 1 < NB) ? h[b2 + 1] : 0;
        int tsum = v0 + v1;
        int x = tsum;
        for (int off = 1; off < 64; off <<= 1) {
            int y = __shfl_up(x, off, 64);
            if (lane >= off) x += y;
        }
        if (lane == 63) wp[wid] = x;
        __syncthreads();
        int wadd = 0;
        for (int k = 0; k < wid; ++k) wadd += wp[k];
        int tpre = wadd + x - tsum;
        if (b2     < NB) exl[b2]     = tpre;
        if (b2 + 1 < NB) exl[b2 + 1] = tpre + v0;
        __syncthreads();
    }
    for (int b = tid; b < NB; b += 512) {
        curb[b] = exl[b];
        gb[b]   = h[b] ? (bucket_base(b, BSPLIT) + atomicAdd(&gcur[b], h[b])) : 0;
    }
    __syncthreads();
    // scatter pass (int4-vectorized)
    j = e0 + tid * 4;
    for (; j + 3 < e1; j += 2048) {
        int4 u4 = *(const int4*)(uu + j);
        int4 v4 = *(const int4*)(vv + j);
        int p;
        p = atomicAdd(&curb[u4.x >> RSHIFT], 1); stage[p] = (v4.x << RSHIFT) | (u4.x & RMASK);
        p = atomicAdd(&curb[v4.x >> RSHIFT], 1); stage[p] = (u4.x << RSHIFT) | (v4.x & RMASK);
        p = atomicAdd(&curb[u4.y >> RSHIFT], 1); stage[p] = (v4.y << RSHIFT) | (u4.y & RMASK);
        p = atomicAdd(&curb[v4.y >> RSHIFT], 1); stage[p] = (u4.y << RSHIFT) | (v4.y & RMASK);
        p = atomicAdd(&curb[u4.z >> RSHIFT], 1); stage[p] = (v4.z << RSHIFT) | (u4.z & RMASK);
        p = atomicAdd(&curb[v4.z >> RSHIFT], 1); stage[p] = (u4.z << RSHIFT) | (v4.z & RMASK);
        p = atomicAdd(&curb[u4.w >> RSHIFT], 1); stage[p] = (v4.w << RSHIFT) | (u4.w & RMASK);
        p = atomicAdd(&curb[v4.w >> RSHIFT], 1); stage[p] = (u4.w << RSHIFT) | (v4.w & RMASK);
    }
    for (; j < e1; ++j) {
        int u = uu[j], v = vv[j];
        int p1 = atomicAdd(&curb[u >> RSHIFT], 1);
        stage[p1] = (v << RSHIFT) | (u & RMASK);
        int p2 = atomicAdd(&curb[v >> RSHIFT], 1);
        stage[p2] = (u << RSHIFT) | (v & RMASK);
    }
    __syncthreads();
    // copy runs out contiguously — one OCTET per bucket run (runs avg ~12)
    int noct = tid >> 3, osub = tid & 7;
    for (int b = noct; b < NB; b += 64) {
        int cnt_b = h[b];
        int st = exl[b], g = gb[b];
        for (int k = osub; k < cnt_b; k += 8) bin[g + k] = stage[st + k];
    }
}

// ---------------- csr: per-bucket LDS counting sort + fused w0 (T=512) ----------------
// outst staging RESTORED (r19 lesson: coalesced full-line col_idx writes
// beat 3->4 blk/CU occupancy). Item buckets (2x cost) scheduled FIRST.

__global__ __launch_bounds__(512) void csr_kernel(const int* __restrict__ bin,
                                                  const int* __restrict__ gcur,
                                                  int* __restrict__ row_ptr,
                                                  int* __restrict__ deg,
                                                  int* __restrict__ col_idx,
                                                  const float4* __restrict__ ue,
                                                  const float4* __restrict__ ie,
                                                  unsigned* __restrict__ w0x,
                                                  int N, int U, int BSPLIT, int NB) {
    __shared__ int h2[256], cur2[256];
    __shared__ float rs2[256];
    __shared__ int wp[8];
    __shared__ __align__(16) int outst[OUT_CAP];
    int nbi = NB - BSPLIT;          // item-bucket count
    int bb  = blockIdx.x;
    int b   = (bb < nbi) ? (BSPLIT + bb) : (bb - nbi);   // items first
    int tid = threadIdx.x;
    int lane = tid & 63, wid = tid >> 6;
    int s = bucket_base(b, BSPLIT);
    int cnt = gcur[b];        // bucket count (offset accumulated by split)
    if (tid < 256) h2[tid] = 0;
    __syncthreads();
    // hist pass (int4; s is 16B aligned)
    int cnt4 = cnt >> 2;
    const int4* bin4 = (const int4*)(bin + s);
    for (int j = tid; j < cnt4; j += 512) {
        int4 v = bin4[j];
        atomicAdd(&h2[v.x & RMASK], 1);
        atomicAdd(&h2[v.y & RMASK], 1);
        atomicAdd(&h2[v.z & RMASK], 1);
        atomicAdd(&h2[v.w & RMASK], 1);
    }
    for (int j = (cnt4 << 2) + tid; j < cnt; j += 512) atomicAdd(&h2[bin[s + j] & RMASK], 1);
    __syncthreads();
    int myh = (tid < 256) ? h2[tid] : 0;
    if (tid < 256) rs2[tid] = (myh > 0) ? rsqrtf((float)myh) : 0.0f;
    // exclusive scan of h2 via wave shuffles (first 4 waves carry data)
    {
        int x = myh;
        for (int off = 1; off < 64; off <<= 1) {
            int y = __shfl_up(x, off, 64);
            if (lane >= off) x += y;
        }
        if (lane == 63) wp[wid] = x;
        __syncthreads();
        if (tid < 256) {
            int wadd = 0;
            for (int k = 0; k < wid; ++k) wadd += wp[k];
            cur2[tid] = wadd + x - myh;   // exclusive
        }
    }
    int gr = (b << RSHIFT) + tid;
    if (tid < 256 && gr < N) {
        row_ptr[gr] = s + cur2[tid];
        deg[gr]     = myh;
    }
    __syncthreads();
    // placement pass (LDS staging)
    if (cnt <= OUT_CAP) {
        for (int j = tid; j < cnt4; j += 512) {
            int4 v = bin4[j];
            int p;
            p = atomicAdd(&cur2[v.x & RMASK], 1); outst[p] = v.x >> RSHIFT;
            p = atomicAdd(&cur2[v.y & RMASK], 1); outst[p] = v.y >> RSHIFT;
            p = atomicAdd(&cur2[v.z & RMASK], 1); outst[p] = v.z >> RSHIFT;
            p = atomicAdd(&cur2[v.w & RMASK], 1); outst[p] = v.w >> RSHIFT;
        }
        for (int j = (cnt4 << 2) + tid; j < cnt; j += 512) {
            int v = bin[s + j];
            int p = atomicAdd(&cur2[v & RMASK], 1);
            outst[p] = v >> RSHIFT;
        }
        __syncthreads();
        // coalesced copy-out: full 16B lanes (r4 rule)
        int4* dst4 = (int4*)(col_idx + s);
        for (int j = tid; j < cnt4; j += 512) dst4[j] = ((const int4*)outst)[j];
        for (int j = (cnt4 << 2) + tid; j < cnt; j += 512) col_idx[s + j] = outst[j];
    } else {  // safety fallback
        for (int j = tid; j < cnt; j += 512) {
            int v = bin[s + j];
            int p = atomicAdd(&cur2[v & RMASK], 1);
            col_idx[s + p] = v >> RSHIFT;
        }
    }
    // fused w0: pack bf16(D^{-1/2} * emb) for this bucket's 256 rows
    // float4 loads (16B/lane), uint2 writes (8B/lane); needs only rs2
    for (int idx = tid; idx < 256 * 16; idx += 512) {
        int rl = idx >> 4, sub = idx & 15;
        int n = (b << RSHIFT) + rl;
        if (n < N) {
            float4 v = (n < U) ? ue[(size_t)n * 16 + sub] : ie[(size_t)(n - U) * 16 + sub];
            float rs = rs2[rl];
            uint2 o;
            o.x = bf16pair(v.x * rs, v.y * rs);
            o.y = bf16pair(v.z * rs, v.w * rs);
            ((uint2*)w0x)[(size_t)n * 16 + sub] = o;
        }
    }
}

// ---------------- SpMM: neighbor mean, octet-per-row (adjacent), unroll-4 ----------------

__global__ __launch_bounds__(256) void spmm_kernel(const int* __restrict__ row_ptr,
                                                   const int* __restrict__ deg,
                                                   const int* __restrict__ col_idx,
                                                   const uint4* __restrict__ x4,
                                                   uint4* __restrict__ y4, int N) {
    int gw   = (blockIdx.x * blockDim.x + threadIdx.x) >> 6;
    int lane = threadIdx.x & 63;
    int oct  = lane >> 3, sub = lane & 7;
    int r = gw * 8 + oct;
    if (r >= N) return;
    int s = row_ptr[r];
    int d = deg[r];
    float2 a0 = {0, 0}, a1 = {0, 0}, a2 = {0, 0}, a3 = {0, 0};
    int k = 0;
    for (; k + 3 < d; k += 4) {
        int c0 = col_idx[s + k];
        int c1 = col_idx[s + k + 1];
        int c2 = col_idx[s + k + 2];
        int c3 = col_idx[s + k + 3];
        uint4 u0 = x4[(size_t)c0 * 8 + sub];
        uint4 u1 = x4[(size_t)c1 * 8 + sub];
        uint4 u2 = x4[(size_t)c2 * 8 + sub];
        uint4 u3 = x4[(size_t)c3 * 8 + sub];
        a0.x += bf_lo(u0.x); a0.y += bf_hi(u0.x);
        a1.x += bf_lo(u0.y); a1.y += bf_hi(u0.y);
        a2.x += bf_lo(u0.z); a2.y += bf_hi(u0.z);
        a3.x += bf_lo(u0.w); a3.y += bf_hi(u0.w);
        a0.x += bf_lo(u1.x); a0.y += bf_hi(u1.x);
        a1.x += bf_lo(u1.y); a1.y += bf_hi(u1.y);
        a2.x += bf_lo(u1.z); a2.y += bf_hi(u1.z);
        a3.x += bf_lo(u1.w); a3.y += bf_hi(u1.w);
        a0.x += bf_lo(u2.x); a0.y += bf_hi(u2.x);
        a1.x += bf_lo(u2.y); a1.y += bf_hi(u2.y);
        a2.x += bf_lo(u2.z); a2.y += bf_hi(u2.z);
        a3.x += bf_lo(u2.w); a3.y += bf_hi(u2.w);
        a0.x += bf_lo(u3.x); a0.y += bf_hi(u3.x);
        a1.x += bf_lo(u3.y); a1.y += bf_hi(u3.y);
        a2.x += bf_lo(u3.z); a2.y += bf_hi(u3.z);
        a3.x += bf_lo(u3.w); a3.y += bf_hi(u3.w);
    }
    for (; k < d; ++k) {
        int c0 = col_idx[s + k];
        uint4 u0 = x4[(size_t)c0 * 8 + sub];
        a0.x += bf_lo(u0.x); a0.y += bf_hi(u0.x);
        a1.x += bf_lo(u0.y); a1.y += bf_hi(u0.y);
        a2.x += bf_lo(u0.z); a2.y += bf_hi(u0.z);
        a3.x += bf_lo(u0.w); a3.y += bf_hi(u0.w);
    }
    float inv = (d > 0) ? (1.0f / (float)d) : 0.0f;
    uint4 o;
    o.x = bf16pair(a0.x * inv, a0.y * inv);
    o.y = bf16pair(a1.x * inv, a1.y * inv);
    o.z = bf16pair(a2.x * inv, a2.y * inv);
    o.w = bf16pair(a3.x * inv, a3.y * inv);
    y4[(size_t)r * 8 + sub] = o;
}

// ---------------- fused layer-3 + readout ----------------
// 8 batch pairs per 128-thread block: octets 0-7 = user rows, 8-15 = item rows.
// Each octet computes its row's L3 (mean over neighbors of L2) in f32,
// adds L1+L2 rows, then the dot is reduced via LDS exchange + octet shuffle.

__global__ __launch_bounds__(128) void batch_readout_kernel(const int* __restrict__ row_ptr,
                                                            const int* __restrict__ deg,
                                                            const int* __restrict__ col_idx,
                                                            const uint4* __restrict__ x4,   // L2
                                                            const uint4* __restrict__ l1,
                                                            const uint4* __restrict__ l2,
                                                            const int* __restrict__ user_ids,
                                                            const int* __restrict__ item_ids,
                                                            float* __restrict__ out,
                                                            int B, int U) {
    __shared__ float sm[8][8][8];    // item-side 3-layer sums
    __shared__ float dsm[8];         // item-side degrees
    int tid = threadIdx.x;
    int oct = tid >> 3, sub = tid & 7;
    int pair = oct & 7, is_item = oct >> 3;
    int b = blockIdx.x * 8 + pair;
    bool active = (b < B);
    float sv[8];
#pragma unroll
    for (int k = 0; k < 8; ++k) sv[k] = 0.0f;
    float dd = 0.0f;
    if (active) {
        int r = is_item ? (item_ids[b] + U) : user_ids[b];
        int s = row_ptr[r];
        int d = deg[r];
        dd = (float)d;
        float2 a0 = {0, 0}, a1 = {0, 0}, a2 = {0, 0}, a3 = {0, 0};
        int k = 0;
        for (; k + 3 < d; k += 4) {
            int c0 = col_idx[s + k];
            int c1 = col_idx[s + k + 1];
            int c2 = col_idx[s + k + 2];
            int c3 = col_idx[s + k + 3];
            uint4 u0 = x4[(size_t)c0 * 8 + sub];
            uint4 u1 = x4[(size_t)c1 * 8 + sub];
            uint4 u2 = x4[(size_t)c2 * 8 + sub];
            uint4 u3 = x4[(size_t)c3 * 8 + sub];
            a0.x += bf_lo(u0.x); a0.y += bf_hi(u0.x);
            a1.x += bf_lo(u0.y); a1.y += bf_hi(u0.y);
            a2.x += bf_lo(u0.z); a2.y += bf_hi(u0.z);
            a3.x += bf_lo(u0.w); a3.y += bf_hi(u0.w);
            a0.x += bf_lo(u1.x); a0.y += bf_hi(u1.x);
            a1.x += bf_lo(u1.y); a1.y += bf_hi(u1.y);
            a2.x += bf_lo(u1.z); a2.y += bf_hi(u1.z);
            a3.x += bf_lo(u1.w); a3.y += bf_hi(u1.w);
            a0.x += bf_lo(u2.x); a0.y += bf_hi(u2.x);
            a1.x += bf_lo(u2.y); a1.y += bf_hi(u2.y);
            a2.x += bf_lo(u2.z); a2.y += bf_hi(u2.z);
            a3.x += bf_lo(u2.w); a3.y += bf_hi(u2.w);
            a0.x += bf_lo(u3.x); a0.y += bf_hi(u3.x);
            a1.x += bf_lo(u3.y); a1.y += bf_hi(u3.y);
            a2.x += bf_lo(u3.z); a2.y += bf_hi(u3.z);
            a3.x += bf_lo(u3.w); a3.y += bf_hi(u3.w);
        }
        for (; k < d; ++k) {
            int c0 = col_idx[s + k];
            uint4 u0 = x4[(size_t)c0 * 8 + sub];
            a0.x += bf_lo(u0.x); a0.y += bf_hi(u0.x);
            a1.x += bf_lo(u0.y); a1.y += bf_hi(u0.y);
            a2.x += bf_lo(u0.z); a2.y += bf_hi(u0.z);
            a3.x += bf_lo(u0.w); a3.y += bf_hi(u0.w);
        }
        float inv = (d > 0) ? (1.0f / (float)d) : 0.0f;
        uint4 u1v = l1[(size_t)r * 8 + sub];
        uint4 u2v = l2[(size_t)r * 8 + sub];
        sv[0] = bf_lo(u1v.x) + bf_lo(u2v.x) + a0.x * inv;
        sv[1] = bf_hi(u1v.x) + bf_hi(u2v.x) + a0.y * inv;
        sv[2] = bf_lo(u1v.y) + bf_lo(u2v.y) + a1.x * inv;
        sv[3] = bf_hi(u1v.y) + bf_hi(u2v.y) + a1.y * inv;
        sv[4] = bf_lo(u1v.z) + bf_lo(u2v.z) + a2.x * inv;
        sv[5] = bf_hi(u1v.z) + bf_hi(u2v.z) + a2.y * inv;
        sv[6] = bf_lo(u1v.w) + bf_lo(u2v.w) + a3.x * inv;
        sv[7] = bf_hi(u1v.w) + bf_hi(u2v.w) + a3.y * inv;
    }
    if (is_item) {
#pragma unroll
        for (int k = 0; k < 8; ++k) sm[pair][sub][k] = sv[k];
        if (sub == 0) dsm[pair] = dd;
    }
    __syncthreads();
    if (!is_item && active) {
        float p = 0.0f;
#pragma unroll
        for (int k = 0; k < 8; ++k) p += sv[k] * sm[pair][sub][k];
#pragma unroll
        for (int off = 4; off > 0; off >>= 1) p += __shfl_down(p, off, 8);
        if (sub == 0) {
            float du = dd;
            float di = dsm[pair];
            out[b] = p * sqrtf(du) * sqrtf(di) * (1.0f / (NUM_LAYERS * NUM_LAYERS));
        }
    }
}

// ---------------- launch ----------------

extern "C" void kernel_launch(void* const* d_in, const int* in_sizes, int n_in,
                              void* d_out, int out_size, void* d_ws, size_t ws_size,
                              hipStream_t stream) {
    const float* user_emb = (const float*)d_in[0];
    const float* item_emb = (const float*)d_in[1];
    // d_in[2] (vals) unused: reconstructed algebraically from degrees
    const int*   rows     = (const int*)d_in[3];
    const int*   cols     = (const int*)d_in[4];
    const int*   user_ids = (const int*)d_in[5];
    const int*   item_ids = (const int*)d_in[6];
    float*       out      = (float*)d_out;

    const int U = in_sizes[0] / EMBED_DIM;
    const int I = in_sizes[1] / EMBED_DIM;
    const int E2 = in_sizes[3] >> 1;    // base pairs: rows=[u;v'], cols=[v';u]
    const int B = in_sizes[5];
    const int N = U + I;
    const int NB = (N + RMASK) >> RSHIFT;   // 256-row buckets
    const int BSPLIT = U >> RSHIFT;         // buckets below: pure users

    // total bin entries = bucket_base(NB)
    const long long TOT = (long long)((NB < BSPLIT ? NB : BSPLIT)) * CAPU +
                          (long long)((NB > BSPLIT) ? (NB - BSPLIT) : 0) * CAPI;

    // workspace layout (~104MB)
    char* w = (char*)d_ws;
    unsigned* x2      = (unsigned*)w; w += (size_t)N * 32 * sizeof(unsigned);   // w0
    unsigned* L1      = (unsigned*)w; w += (size_t)N * 32 * sizeof(unsigned);
    unsigned* L2      = (unsigned*)w; w += (size_t)N * 32 * sizeof(unsigned);
    int*      bin     = (int*)w;      w += (size_t)TOT * sizeof(int);
    int*      col_idx = (int*)w;      w += (size_t)TOT * sizeof(int);
    int*      row_ptr = (int*)w;      w += (size_t)N * sizeof(int);
    int*      deg     = (int*)w;      w += (size_t)N * sizeof(int);
    int*      gcur    = (int*)w;      w += (size_t)NB * sizeof(int);

    const int GP = (E2 + TP - 1) / TP;

    // CSR build: split-capacity buckets, LDS-staged counting sort, fused w0
    hipMemsetAsync(gcur, 0, (size_t)NB * sizeof(int), stream);
    split_kernel<<<GP, 512, 0, stream>>>(rows, cols, gcur, bin, E2, NB, BSPLIT);
    csr_kernel<<<NB, 512, 0, stream>>>(bin, gcur, row_ptr, deg, col_idx,
                                       (const float4*)user_emb, (const float4*)item_emb,
                                       x2, N, U, BSPLIT, NB);

    // propagation: layers 1-2 full (structural fill floor), layer 3 fused into readout
    const int T = 256;
    const int GS = (N * 8 + T - 1) / T;   // one octet (8 threads) per row
    spmm_kernel<<<GS, T, 0, stream>>>(row_ptr, deg, col_idx,
                                      (const uint4*)x2, (uint4*)L1, N);
    spmm_kernel<<<GS, T, 0, stream>>>(row_ptr, deg, col_idx,
                                      (const uint4*)L1, (uint4*)L2, N);

    batch_readout_kernel<<<(B + 7) / 8, 128, 0, stream>>>(row_ptr, deg, col_idx,
                                                          (const uint4*)L2,
                                                          (const uint4*)L1, (const uint4*)L2,
                                                          user_ids, item_ids, out, B, U);
}

// Round 6
// 282.193 us; speedup vs baseline: 1.1009x; 1.0189x over previous
//
#include <hip/hip_runtime.h>

// XSimGCL / LightGCN propagation on MI355X.
// w = D^{-1/2} x  =>  each layer is an unweighted neighbor MEAN; no edge values.
// State = packed bf16 pairs, 128B rows.
// r16 lesson: fp8 e4m3 state FAILED accuracy: relative quant noise does NOT
//   average down through mean-propagation. State stays bf16.
// r17: layer-3 batch-restricted (2B rows) — worked (-57us).
// r18: T=512 build, gcur offsets+memset, fused L3+readout (-16us).
// r19 lesson: direct col_idx scatter REGRESSED (+22us): random 4B global
//   writes. r4 rule (contiguous/full-line global writes) is load-bearing.
// r20: staging restored; accounting CLOSES: spmm 126.6 + build ~45 + harness
//   reset ~100us fixed (40-80 tiny memset dispatches/iter inside timed
//   region). spmm FETCH 182MB is within ~4% of the compulsory per-XCD fill
//   floor (8x19.2 state + 16 col_idx) -> locality tricks capped at ~3us;
//   dropped. Controllable slack ~15-20us of build latency.
// r21: wider build blocks: split T=1024/TP=7168 (280 blocks, halves per-block
//   scan/barrier fixed cost, runs ~24 -> less copy waste + less bin RMW);
//   csr T=1024 (32 waves/CU vs 24); row_ptr+deg folded into int2 rpd.
// spmm L1/L2: at structural fill floor, ~3.27 TB/s random-128B fill.
//   octet-per-row on ADJACENT rows, unroll-4 (r13 best).

#define EMBED_DIM 64
#define NUM_LAYERS 3
#define RSHIFT 8            // 256 rows per bucket
#define RMASK 255
#define NBMAX 640           // supports N <= 163840
#define CAPU 8192           // user-bucket capacity (mean 5120)
#define CAPI 12288          // item-bucket capacity (mean 10240)
#define TP 7168             // base pairs per tile -> 2*TP staged entries
#define OUT_CAP 12288       // csr out-staging capacity (>= worst bucket)

__device__ __forceinline__ int bucket_base(int b, int BSPLIT) {
    int lo = (b < BSPLIT) ? b : BSPLIT;
    int hi = (b > BSPLIT) ? (b - BSPLIT) : 0;
    return lo * CAPU + hi * CAPI;
}

// ---------------- bf16 pair helpers ----------------

__device__ __forceinline__ unsigned bf16pair(float a, float b) {
    unsigned ia = __float_as_uint(a);
    unsigned ib = __float_as_uint(b);
    ia = (ia + 0x7fffu + ((ia >> 16) & 1u)) >> 16;          // RNE, low half
    ib = (ib + 0x7fffu + ((ib >> 16) & 1u)) & 0xffff0000u;  // RNE, high half
    return ia | ib;
}
__device__ __forceinline__ float bf_lo(unsigned u) { return __uint_as_float(u << 16); }
__device__ __forceinline__ float bf_hi(unsigned u) { return __uint_as_float(u & 0xffff0000u); }

// ---------------- split: pairs -> 2 entries -> LDS bucket-grouped -> run copies ----------------
// T=1024, TP=7168 (LDS ~68KB -> 2 blk/CU = 32 waves/CU).
// gcur[b] holds per-bucket OFFSET (memset-0 before launch).

__global__ __launch_bounds__(1024) void split_kernel(const int* __restrict__ uu,
                                                     const int* __restrict__ vv,
                                                     int* __restrict__ gcur,
                                                     int* __restrict__ bin, int E2, int NB,
                                                     int BSPLIT) {
    __shared__ int h[NBMAX], exl[NBMAX], curb[NBMAX], gb[NBMAX];
    __shared__ int wp[16];
    __shared__ int stage[2 * TP];
    int tid = threadIdx.x;
    int lane = tid & 63, wid = tid >> 6;
    for (int i = tid; i < NB; i += 1024) h[i] = 0;
    __syncthreads();
    int e0 = blockIdx.x * TP, e1 = min(e0 + TP, E2);
    // hist pass (int4-vectorized; e0 is 16B aligned)
    int j = e0 + tid * 4;
    for (; j + 3 < e1; j += 4096) {
        int4 u4 = *(const int4*)(uu + j);
        int4 v4 = *(const int4*)(vv + j);
        atomicAdd(&h[u4.x >> RSHIFT], 1); atomicAdd(&h[v4.x >> RSHIFT], 1);
        atomicAdd(&h[u4.y >> RSHIFT], 1); atomicAdd(&h[v4.y >> RSHIFT], 1);
        atomicAdd(&h[u4.z >> RSHIFT], 1); atomicAdd(&h[v4.z >> RSHIFT], 1);
        atomicAdd(&h[u4.w >> RSHIFT], 1); atomicAdd(&h[v4.w >> RSHIFT], 1);
    }
    for (; j < e1; ++j) {  // tail (last block only)
        atomicAdd(&h[uu[j] >> RSHIFT], 1);
        atomicAdd(&h[vv[j] >> RSHIFT], 1);
    }
    __syncthreads();
    // exclusive scan of h[0..NB): 1 elem/thread + wave-shuffle scan (16 waves)
    {
        int v0 = (tid < NB) ? h[tid] : 0;
        int x = v0;
        for (int off = 1; off < 64; off <<= 1) {
            int y = __shfl_up(x, off, 64);
            if (lane >= off) x += y;
        }
        if (lane == 63) wp[wid] = x;
        __syncthreads();
        int wadd = 0;
        for (int k = 0; k < wid; ++k) wadd += wp[k];
        if (tid < NB) exl[tid] = wadd + x - v0;
        __syncthreads();
    }
    for (int b = tid; b < NB; b += 1024) {
        curb[b] = exl[b];
        gb[b]   = h[b] ? (bucket_base(b, BSPLIT) + atomicAdd(&gcur[b], h[b])) : 0;
    }
    __syncthreads();
    // scatter pass (int4-vectorized)
    j = e0 + tid * 4;
    for (; j + 3 < e1; j += 4096) {
        int4 u4 = *(const int4*)(uu + j);
        int4 v4 = *(const int4*)(vv + j);
        int p;
        p = atomicAdd(&curb[u4.x >> RSHIFT], 1); stage[p] = (v4.x << RSHIFT) | (u4.x & RMASK);
        p = atomicAdd(&curb[v4.x >> RSHIFT], 1); stage[p] = (u4.x << RSHIFT) | (v4.x & RMASK);
        p = atomicAdd(&curb[u4.y >> RSHIFT], 1); stage[p] = (v4.y << RSHIFT) | (u4.y & RMASK);
        p = atomicAdd(&curb[v4.y >> RSHIFT], 1); stage[p] = (u4.y << RSHIFT) | (v4.y & RMASK);
        p = atomicAdd(&curb[u4.z >> RSHIFT], 1); stage[p] = (v4.z << RSHIFT) | (u4.z & RMASK);
        p = atomicAdd(&curb[v4.z >> RSHIFT], 1); stage[p] = (u4.z << RSHIFT) | (v4.z & RMASK);
        p = atomicAdd(&curb[u4.w >> RSHIFT], 1); stage[p] = (v4.w << RSHIFT) | (u4.w & RMASK);
        p = atomicAdd(&curb[v4.w >> RSHIFT], 1); stage[p] = (u4.w << RSHIFT) | (v4.w & RMASK);
    }
    for (; j < e1; ++j) {
        int u = uu[j], v = vv[j];
        int p1 = atomicAdd(&curb[u >> RSHIFT], 1);
        stage[p1] = (v << RSHIFT) | (u & RMASK);
        int p2 = atomicAdd(&curb[v >> RSHIFT], 1);
        stage[p2] = (u << RSHIFT) | (v & RMASK);
    }
    __syncthreads();
    // copy runs out contiguously — one OCTET per bucket run (runs avg ~24)
    int noct = tid >> 3, osub = tid & 7;
    for (int b = noct; b < NB; b += 128) {
        int cnt_b = h[b];
        int st = exl[b], g = gb[b];
        for (int k = osub; k < cnt_b; k += 8) bin[g + k] = stage[st + k];
    }
}

// ---------------- csr: per-bucket LDS counting sort + fused w0 (T=1024) ----------------
// outst staging (r19 lesson: coalesced full-line col_idx writes are load-
// bearing). Item buckets (2x cost) scheduled FIRST. rpd = {row_ptr, deg}.

__global__ __launch_bounds__(1024) void csr_kernel(const int* __restrict__ bin,
                                                   const int* __restrict__ gcur,
                                                   int2* __restrict__ rpd,
                                                   int* __restrict__ col_idx,
                                                   const float4* __restrict__ ue,
                                                   const float4* __restrict__ ie,
                                                   unsigned* __restrict__ w0x,
                                                   int N, int U, int BSPLIT, int NB) {
    __shared__ int h2[256], cur2[256];
    __shared__ float rs2[256];
    __shared__ int wp[16];
    __shared__ __align__(16) int outst[OUT_CAP];
    int nbi = NB - BSPLIT;          // item-bucket count
    int bb  = blockIdx.x;
    int b   = (bb < nbi) ? (BSPLIT + bb) : (bb - nbi);   // items first
    int tid = threadIdx.x;
    int lane = tid & 63, wid = tid >> 6;
    int s = bucket_base(b, BSPLIT);
    int cnt = gcur[b];        // bucket count (offset accumulated by split)
    if (tid < 256) h2[tid] = 0;
    __syncthreads();
    // hist pass (int4; s is 16B aligned)
    int cnt4 = cnt >> 2;
    const int4* bin4 = (const int4*)(bin + s);
    for (int j = tid; j < cnt4; j += 1024) {
        int4 v = bin4[j];
        atomicAdd(&h2[v.x & RMASK], 1);
        atomicAdd(&h2[v.y & RMASK], 1);
        atomicAdd(&h2[v.z & RMASK], 1);
        atomicAdd(&h2[v.w & RMASK], 1);
    }
    for (int j = (cnt4 << 2) + tid; j < cnt; j += 1024) atomicAdd(&h2[bin[s + j] & RMASK], 1);
    __syncthreads();
    int myh = (tid < 256) ? h2[tid] : 0;
    if (tid < 256) rs2[tid] = (myh > 0) ? rsqrtf((float)myh) : 0.0f;
    // exclusive scan of h2 via wave shuffles (first 4 waves carry data)
    {
        int x = myh;
        for (int off = 1; off < 64; off <<= 1) {
            int y = __shfl_up(x, off, 64);
            if (lane >= off) x += y;
        }
        if (lane == 63) wp[wid] = x;
        __syncthreads();
        if (tid < 256) {
            int wadd = 0;
            for (int k = 0; k < wid; ++k) wadd += wp[k];
            cur2[tid] = wadd + x - myh;   // exclusive
        }
    }
    int gr = (b << RSHIFT) + tid;
    if (tid < 256 && gr < N) {
        int2 v; v.x = s + cur2[tid]; v.y = myh;
        rpd[gr] = v;
    }
    __syncthreads();
    // placement pass (LDS staging)
    if (cnt <= OUT_CAP) {
        for (int j = tid; j < cnt4; j += 1024) {
            int4 v = bin4[j];
            int p;
            p = atomicAdd(&cur2[v.x & RMASK], 1); outst[p] = v.x >> RSHIFT;
            p = atomicAdd(&cur2[v.y & RMASK], 1); outst[p] = v.y >> RSHIFT;
            p = atomicAdd(&cur2[v.z & RMASK], 1); outst[p] = v.z >> RSHIFT;
            p = atomicAdd(&cur2[v.w & RMASK], 1); outst[p] = v.w >> RSHIFT;
        }
        for (int j = (cnt4 << 2) + tid; j < cnt; j += 1024) {
            int v = bin[s + j];
            int p = atomicAdd(&cur2[v & RMASK], 1);
            outst[p] = v >> RSHIFT;
        }
        __syncthreads();
        // coalesced copy-out: full 16B lanes (r4 rule)
        int4* dst4 = (int4*)(col_idx + s);
        for (int j = tid; j < cnt4; j += 1024) dst4[j] = ((const int4*)outst)[j];
        for (int j = (cnt4 << 2) + tid; j < cnt; j += 1024) col_idx[s + j] = outst[j];
    } else {  // safety fallback
        for (int j = tid; j < cnt; j += 1024) {
            int v = bin[s + j];
            int p = atomicAdd(&cur2[v & RMASK], 1);
            col_idx[s + p] = v >> RSHIFT;
        }
    }
    // fused w0: pack bf16(D^{-1/2} * emb) for this bucket's 256 rows
    // float4 loads (16B/lane), uint2 writes (8B/lane); needs only rs2
    for (int idx = tid; idx < 256 * 16; idx += 1024) {
        int rl = idx >> 4, sub = idx & 15;
        int n = (b << RSHIFT) + rl;
        if (n < N) {
            float4 v = (n < U) ? ue[(size_t)n * 16 + sub] : ie[(size_t)(n - U) * 16 + sub];
            float rs = rs2[rl];
            uint2 o;
            o.x = bf16pair(v.x * rs, v.y * rs);
            o.y = bf16pair(v.z * rs, v.w * rs);
            ((uint2*)w0x)[(size_t)n * 16 + sub] = o;
        }
    }
}

// ---------------- SpMM: neighbor mean, octet-per-row (adjacent), unroll-4 ----------------

__global__ __launch_bounds__(256) void spmm_kernel(const int2* __restrict__ rpd,
                                                   const int* __restrict__ col_idx,
                                                   const uint4* __restrict__ x4,
                                                   uint4* __restrict__ y4, int N) {
    int gw   = (blockIdx.x * blockDim.x + threadIdx.x) >> 6;
    int lane = threadIdx.x & 63;
    int oct  = lane >> 3, sub = lane & 7;
    int r = gw * 8 + oct;
    if (r >= N) return;
    int2 rd = rpd[r];
    int s = rd.x;
    int d = rd.y;
    float2 a0 = {0, 0}, a1 = {0, 0}, a2 = {0, 0}, a3 = {0, 0};
    int k = 0;
    for (; k + 3 < d; k += 4) {
        int c0 = col_idx[s + k];
        int c1 = col_idx[s + k + 1];
        int c2 = col_idx[s + k + 2];
        int c3 = col_idx[s + k + 3];
        uint4 u0 = x4[(size_t)c0 * 8 + sub];
        uint4 u1 = x4[(size_t)c1 * 8 + sub];
        uint4 u2 = x4[(size_t)c2 * 8 + sub];
        uint4 u3 = x4[(size_t)c3 * 8 + sub];
        a0.x += bf_lo(u0.x); a0.y += bf_hi(u0.x);
        a1.x += bf_lo(u0.y); a1.y += bf_hi(u0.y);
        a2.x += bf_lo(u0.z); a2.y += bf_hi(u0.z);
        a3.x += bf_lo(u0.w); a3.y += bf_hi(u0.w);
        a0.x += bf_lo(u1.x); a0.y += bf_hi(u1.x);
        a1.x += bf_lo(u1.y); a1.y += bf_hi(u1.y);
        a2.x += bf_lo(u1.z); a2.y += bf_hi(u1.z);
        a3.x += bf_lo(u1.w); a3.y += bf_hi(u1.w);
        a0.x += bf_lo(u2.x); a0.y += bf_hi(u2.x);
        a1.x += bf_lo(u2.y); a1.y += bf_hi(u2.y);
        a2.x += bf_lo(u2.z); a2.y += bf_hi(u2.z);
        a3.x += bf_lo(u2.w); a3.y += bf_hi(u2.w);
        a0.x += bf_lo(u3.x); a0.y += bf_hi(u3.x);
        a1.x += bf_lo(u3.y); a1.y += bf_hi(u3.y);
        a2.x += bf_lo(u3.z); a2.y += bf_hi(u3.z);
        a3.x += bf_lo(u3.w); a3.y += bf_hi(u3.w);
    }
    for (; k < d; ++k) {
        int c0 = col_idx[s + k];
        uint4 u0 = x4[(size_t)c0 * 8 + sub];
        a0.x += bf_lo(u0.x); a0.y += bf_hi(u0.x);
        a1.x += bf_lo(u0.y); a1.y += bf_hi(u0.y);
        a2.x += bf_lo(u0.z); a2.y += bf_hi(u0.z);
        a3.x += bf_lo(u0.w); a3.y += bf_hi(u0.w);
    }
    float inv = (d > 0) ? (1.0f / (float)d) : 0.0f;
    uint4 o;
    o.x = bf16pair(a0.x * inv, a0.y * inv);
    o.y = bf16pair(a1.x * inv, a1.y * inv);
    o.z = bf16pair(a2.x * inv, a2.y * inv);
    o.w = bf16pair(a3.x * inv, a3.y * inv);
    y4[(size_t)r * 8 + sub] = o;
}

// ---------------- fused layer-3 + readout ----------------
// 8 batch pairs per 128-thread block: octets 0-7 = user rows, 8-15 = item rows.

__global__ __launch_bounds__(128) void batch_readout_kernel(const int2* __restrict__ rpd,
                                                            const int* __restrict__ col_idx,
                                                            const uint4* __restrict__ x4,   // L2
                                                            const uint4* __restrict__ l1,
                                                            const uint4* __restrict__ l2,
                                                            const int* __restrict__ user_ids,
                                                            const int* __restrict__ item_ids,
                                                            float* __restrict__ out,
                                                            int B, int U) {
    __shared__ float sm[8][8][8];    // item-side 3-layer sums
    __shared__ float dsm[8];         // item-side degrees
    int tid = threadIdx.x;
    int oct = tid >> 3, sub = tid & 7;
    int pair = oct & 7, is_item = oct >> 3;
    int b = blockIdx.x * 8 + pair;
    bool active = (b < B);
    float sv[8];
#pragma unroll
    for (int k = 0; k < 8; ++k) sv[k] = 0.0f;
    float dd = 0.0f;
    if (active) {
        int r = is_item ? (item_ids[b] + U) : user_ids[b];
        int2 rd = rpd[r];
        int s = rd.x;
        int d = rd.y;
        dd = (float)d;
        float2 a0 = {0, 0}, a1 = {0, 0}, a2 = {0, 0}, a3 = {0, 0};
        int k = 0;
        for (; k + 3 < d; k += 4) {
            int c0 = col_idx[s + k];
            int c1 = col_idx[s + k + 1];
            int c2 = col_idx[s + k + 2];
            int c3 = col_idx[s + k + 3];
            uint4 u0 = x4[(size_t)c0 * 8 + sub];
            uint4 u1 = x4[(size_t)c1 * 8 + sub];
            uint4 u2 = x4[(size_t)c2 * 8 + sub];
            uint4 u3 = x4[(size_t)c3 * 8 + sub];
            a0.x += bf_lo(u0.x); a0.y += bf_hi(u0.x);
            a1.x += bf_lo(u0.y); a1.y += bf_hi(u0.y);
            a2.x += bf_lo(u0.z); a2.y += bf_hi(u0.z);
            a3.x += bf_lo(u0.w); a3.y += bf_hi(u0.w);
            a0.x += bf_lo(u1.x); a0.y += bf_hi(u1.x);
            a1.x += bf_lo(u1.y); a1.y += bf_hi(u1.y);
            a2.x += bf_lo(u1.z); a2.y += bf_hi(u1.z);
            a3.x += bf_lo(u1.w); a3.y += bf_hi(u1.w);
            a0.x += bf_lo(u2.x); a0.y += bf_hi(u2.x);
            a1.x += bf_lo(u2.y); a1.y += bf_hi(u2.y);
            a2.x += bf_lo(u2.z); a2.y += bf_hi(u2.z);
            a3.x += bf_lo(u2.w); a3.y += bf_hi(u2.w);
            a0.x += bf_lo(u3.x); a0.y += bf_hi(u3.x);
            a1.x += bf_lo(u3.y); a1.y += bf_hi(u3.y);
            a2.x += bf_lo(u3.z); a2.y += bf_hi(u3.z);
            a3.x += bf_lo(u3.w); a3.y += bf_hi(u3.w);
        }
        for (; k < d; ++k) {
            int c0 = col_idx[s + k];
            uint4 u0 = x4[(size_t)c0 * 8 + sub];
            a0.x += bf_lo(u0.x); a0.y += bf_hi(u0.x);
            a1.x += bf_lo(u0.y); a1.y += bf_hi(u0.y);
            a2.x += bf_lo(u0.z); a2.y += bf_hi(u0.z);
            a3.x += bf_lo(u0.w); a3.y += bf_hi(u0.w);
        }
        float inv = (d > 0) ? (1.0f / (float)d) : 0.0f;
        uint4 u1v = l1[(size_t)r * 8 + sub];
        uint4 u2v = l2[(size_t)r * 8 + sub];
        sv[0] = bf_lo(u1v.x) + bf_lo(u2v.x) + a0.x * inv;
        sv[1] = bf_hi(u1v.x) + bf_hi(u2v.x) + a0.y * inv;
        sv[2] = bf_lo(u1v.y) + bf_lo(u2v.y) + a1.x * inv;
        sv[3] = bf_hi(u1v.y) + bf_hi(u2v.y) + a1.y * inv;
        sv[4] = bf_lo(u1v.z) + bf_lo(u2v.z) + a2.x * inv;
        sv[5] = bf_hi(u1v.z) + bf_hi(u2v.z) + a2.y * inv;
        sv[6] = bf_lo(u1v.w) + bf_lo(u2v.w) + a3.x * inv;
        sv[7] = bf_hi(u1v.w) + bf_hi(u2v.w) + a3.y * inv;
    }
    if (is_item) {
#pragma unroll
        for (int k = 0; k < 8; ++k) sm[pair][sub][k] = sv[k];
        if (sub == 0) dsm[pair] = dd;
    }
    __syncthreads();
    if (!is_item && active) {
        float p = 0.0f;
#pragma unroll
        for (int k = 0; k < 8; ++k) p += sv[k] * sm[pair][sub][k];
#pragma unroll
        for (int off = 4; off > 0; off >>= 1) p += __shfl_down(p, off, 8);
        if (sub == 0) {
            float du = dd;
            float di = dsm[pair];
            out[b] = p * sqrtf(du) * sqrtf(di) * (1.0f / (NUM_LAYERS * NUM_LAYERS));
        }
    }
}

// ---------------- launch ----------------

extern "C" void kernel_launch(void* const* d_in, const int* in_sizes, int n_in,
                              void* d_out, int out_size, void* d_ws, size_t ws_size,
                              hipStream_t stream) {
    const float* user_emb = (const float*)d_in[0];
    const float* item_emb = (const float*)d_in[1];
    // d_in[2] (vals) unused: reconstructed algebraically from degrees
    const int*   rows     = (const int*)d_in[3];
    const int*   cols     = (const int*)d_in[4];
    const int*   user_ids = (const int*)d_in[5];
    const int*   item_ids = (const int*)d_in[6];
    float*       out      = (float*)d_out;

    const int U = in_sizes[0] / EMBED_DIM;
    const int I = in_sizes[1] / EMBED_DIM;
    const int E2 = in_sizes[3] >> 1;    // base pairs: rows=[u;v'], cols=[v';u]
    const int B = in_sizes[5];
    const int N = U + I;
    const int NB = (N + RMASK) >> RSHIFT;   // 256-row buckets
    const int BSPLIT = U >> RSHIFT;         // buckets below: pure users

    // total bin entries = bucket_base(NB)
    const long long TOT = (long long)((NB < BSPLIT ? NB : BSPLIT)) * CAPU +
                          (long long)((NB > BSPLIT) ? (NB - BSPLIT) : 0) * CAPI;

    // workspace layout
    char* w = (char*)d_ws;
    unsigned* x2      = (unsigned*)w; w += (size_t)N * 32 * sizeof(unsigned);   // w0
    unsigned* L1      = (unsigned*)w; w += (size_t)N * 32 * sizeof(unsigned);
    unsigned* L2      = (unsigned*)w; w += (size_t)N * 32 * sizeof(unsigned);
    int*      bin     = (int*)w;      w += (size_t)TOT * sizeof(int);
    int*      col_idx = (int*)w;      w += (size_t)TOT * sizeof(int);
    int2*     rpd     = (int2*)w;     w += (size_t)N * sizeof(int2);
    int*      gcur    = (int*)w;      w += (size_t)NB * sizeof(int);

    const int GP = (E2 + TP - 1) / TP;

    // CSR build: split-capacity buckets, LDS-staged counting sort, fused w0
    hipMemsetAsync(gcur, 0, (size_t)NB * sizeof(int), stream);
    split_kernel<<<GP, 1024, 0, stream>>>(rows, cols, gcur, bin, E2, NB, BSPLIT);
    csr_kernel<<<NB, 1024, 0, stream>>>(bin, gcur, rpd, col_idx,
                                        (const float4*)user_emb, (const float4*)item_emb,
                                        x2, N, U, BSPLIT, NB);

    // propagation: layers 1-2 full (structural fill floor), layer 3 fused into readout
    const int T = 256;
    const int GS = (N * 8 + T - 1) / T;   // one octet (8 threads) per row
    spmm_kernel<<<GS, T, 0, stream>>>(rpd, col_idx, (const uint4*)x2, (uint4*)L1, N);
    spmm_kernel<<<GS, T, 0, stream>>>(rpd, col_idx, (const uint4*)L1, (uint4*)L2, N);

    batch_readout_kernel<<<(B + 7) / 8, 128, 0, stream>>>(rpd, col_idx,
                                                          (const uint4*)L2,
                                                          (const uint4*)L1, (const uint4*)L2,
                                                          user_ids, item_ids, out, B, U);
}